// Round 3
// baseline (9082.687 us; speedup 1.0000x reference)
//
#include <hip/hip_runtime.h>
#include <math.h>

// MetalWallQEQ: reciprocal-space Ewald QEQ for metal-wall charges.
//  out[i] = q[i] for electrolyte atoms; for metal atoms solve
//  [[A+J I, 1],[1^T,0]][q;lam]=[B;0],  A_ij=(4pi/V) sum_k kfac cos(k.(ri-rj)),
//  B = -field(metal) from electrolyte charges.
// Round 3: CG loop collapsed into ONE persistent kernel (256 blocks = 1/CU)
// with a software grid barrier -> removes ~300 dispatch overheads.

#define NA 4096
#define NM 2048
#define METAL_Z 79
#define KH 7812          // (25^3-1)/2 half k-points
#define KHP 7936         // padded to 62*128 (pad entries have w=0)
#define NIT 150          // fixed CG iterations (graph-friendly)
#define NBLK_CG 256      // persistent CG grid: 1 block/CU, guaranteed co-resident
#define TWO_PI 6.283185307179586f

// ---- workspace byte offsets (total ~17.7 MB) ----
#define OFF_CONSTS 0        // [0..8]=invT(cell) row-major, [9]=pref=4pi/V, [10]=J
#define OFF_SUMS   256      // [2]=lambda
#define OFF_BAR    384      // int[2]: barrier cnt, gen (zeroed per call in k_setup)
#define OFF_DOTS   512      // (unused by persistent CG; kept zeroed)
#define OFF_KTAB   4096     // KHP * {gx,gy,gz,w} floats
#define OFF_FRAC   131072   // NA * {fx,fy,fz,0} fractional coords
#define OFF_MLIST  196608   // NM ints: metal position -> atom index
#define OFF_POSOF  204800   // NA ints: atom -> metal position (metal only)
#define OFF_SRW    221184   // KHP floats: w*Re S(k)
#define OFF_SIW    252928   // KHP floats: w*Im S(k)
#define OFF_BPART  284672   // 62*NM floats: field partials (reused as CG dot partials)
#define OFF_PART   OFF_BPART
#define OFF_B      792576   // NM floats
#define OFF_VEC    800768   // x1,x2,r1,r2 (each NM floats)
#define OFF_A      917504   // NM*NM floats (includes +J on diagonal)

__device__ __forceinline__ void sc_frac(float u, float& s, float& c) {
    float t = u - floorf(u);
    __sincosf(TWO_PI * t, &s, &c);
}

// -------- setup: cell inverse, fractional coords, metal scan, zero state --------
__global__ void k_setup(const float* __restrict__ pos, const float* __restrict__ cell,
                        const float* __restrict__ Jraw, const int* __restrict__ an,
                        float* __restrict__ wsf) {
    int tid = threadIdx.x;
    __shared__ float sM[9];
    __shared__ int sc[256];
    if (tid == 0) {
        float c00=cell[0],c01=cell[1],c02=cell[2];
        float c10=cell[3],c11=cell[4],c12=cell[5];
        float c20=cell[6],c21=cell[7],c22=cell[8];
        float det = c00*(c11*c22-c12*c21) - c01*(c10*c22-c12*c20) + c02*(c10*c21-c11*c20);
        float i00 =  (c11*c22 - c12*c21)/det;
        float i01 = -(c01*c22 - c02*c21)/det;
        float i02 =  (c01*c12 - c02*c11)/det;
        float i10 = -(c10*c22 - c12*c20)/det;
        float i11 =  (c00*c22 - c02*c20)/det;
        float i12 = -(c00*c12 - c02*c10)/det;
        float i20 =  (c10*c21 - c11*c20)/det;
        float i21 = -(c00*c21 - c01*c20)/det;
        float i22 =  (c00*c11 - c01*c10)/det;
        sM[0]=i00; sM[1]=i10; sM[2]=i20;
        sM[3]=i01; sM[4]=i11; sM[5]=i21;
        sM[6]=i02; sM[7]=i12; sM[8]=i22;
        float vol = fabsf(det);
        for (int m=0;m<9;m++) wsf[OFF_CONSTS/4 + m] = sM[m];
        wsf[OFF_CONSTS/4 + 9]  = 12.566370614359172f / vol;   // 4pi/V
        wsf[OFF_CONSTS/4 + 10] = Jraw[0]*Jraw[0];
        ((int*)wsf)[OFF_BAR/4 + 0] = 0;   // barrier cnt
        ((int*)wsf)[OFF_BAR/4 + 1] = 0;   // barrier gen
    }
    __syncthreads();
    float M0=sM[0],M1=sM[1],M2=sM[2],M3=sM[3],M4=sM[4],M5=sM[5],M6=sM[6],M7=sM[7],M8=sM[8];
    for (int i=tid; i<NA; i+=256) {
        float x=pos[3*i], y=pos[3*i+1], z=pos[3*i+2];
        wsf[OFF_FRAC/4 + 4*i+0] = M0*x + M1*y + M2*z;
        wsf[OFF_FRAC/4 + 4*i+1] = M3*x + M4*y + M5*z;
        wsf[OFF_FRAC/4 + 4*i+2] = M6*x + M7*y + M8*z;
        wsf[OFF_FRAC/4 + 4*i+3] = 0.f;
    }
    for (int i=tid; i<4*NIT+4; i+=256) wsf[OFF_DOTS/4 + i] = 0.f;
    if (tid < 4) wsf[OFF_SUMS/4 + tid] = 0.f;
    // metal prefix scan (deterministic ordering == np.where order)
    int cnt = 0;
    int base_i = tid*16;
    for (int j=0;j<16;j++) cnt += (an[base_i+j]==METAL_Z) ? 1 : 0;
    sc[tid] = cnt; __syncthreads();
    for (int off=1; off<256; off<<=1) {
        int v = (tid>=off) ? sc[tid-off] : 0;
        __syncthreads();
        sc[tid] += v;
        __syncthreads();
    }
    int base = sc[tid] - cnt;
    int* mlist = (int*)wsf + OFF_MLIST/4;
    int* posof = (int*)wsf + OFF_POSOF/4;
    for (int j=0;j<16;j++) {
        int i = base_i + j;
        if (an[i]==METAL_Z) { mlist[base] = i; posof[i] = base; base++; }
    }
}

// -------- k-table: integer triple + weight w = 2*pref*exp(-k2/2)/k2 --------
__global__ void k_ktab(float* __restrict__ wsf) {
    int k = blockIdx.x*256 + threadIdx.x;
    if (k >= KHP) return;
    float4 out;
    if (k < KH) {
        int gx = k/625 - 12;
        int rem = k%625;
        int gy = rem/25 - 12;
        int gz = rem%25 - 12;
        const float* M = wsf + OFF_CONSTS/4;
        float pref = M[9];
        float kx = TWO_PI*(gx*M[0] + gy*M[3] + gz*M[6]);
        float ky = TWO_PI*(gx*M[1] + gy*M[4] + gz*M[7]);
        float kz = TWO_PI*(gx*M[2] + gy*M[5] + gz*M[8]);
        float k2 = kx*kx + ky*ky + kz*kz;
        float kfac = __expf(-0.5f*k2) / k2;
        out = make_float4((float)gx, (float)gy, (float)gz, 2.f*pref*kfac);
    } else {
        out = make_float4(0.f, 0.f, 0.f, 0.f);
    }
    *(float4*)(wsf + OFF_KTAB/4 + 4*k) = out;
}

// -------- structure factors over electrolyte charges (metal q := 0) --------
__global__ void k_srsi(const float* __restrict__ q, const int* __restrict__ an,
                       float* __restrict__ wsf) {
    int k = blockIdx.x;
    int tid = threadIdx.x;
    float4 kt = *(const float4*)(wsf + OFF_KTAB/4 + 4*k);
    const float* frac = wsf + OFF_FRAC/4;
    float aR=0.f, aI=0.f;
    for (int i=tid; i<NA; i+=256) {
        float qa = (an[i]==METAL_Z) ? 0.f : q[i];
        float4 f = *(const float4*)(frac + 4*i);
        float u = kt.x*f.x + kt.y*f.y + kt.z*f.z;
        float s,c; sc_frac(u, s, c);
        aR += qa*c; aI += qa*s;
    }
    __shared__ float sR[256], sI[256];
    sR[tid]=aR; sI[tid]=aI; __syncthreads();
    for (int off=128; off>0; off>>=1) {
        if (tid<off) { sR[tid]+=sR[tid+off]; sI[tid]+=sI[tid+off]; }
        __syncthreads();
    }
    if (tid==0) {
        wsf[OFF_SRW/4 + k] = kt.w * sR[0];
        wsf[OFF_SIW/4 + k] = kt.w * sI[0];
    }
}

// -------- field at metal atoms (partial over k-chunks) --------
__global__ void k_field(float* __restrict__ wsf) {
    int kc = blockIdx.x;
    int m = blockIdx.y*256 + threadIdx.x;
    int atom = ((const int*)wsf)[OFF_MLIST/4 + m];
    float4 f = *(const float4*)(wsf + OFF_FRAC/4 + 4*atom);
    const float* kt = wsf + OFF_KTAB/4;
    const float* SrW = wsf + OFF_SRW/4;
    const float* SiW = wsf + OFF_SIW/4;
    float acc = 0.f;
    int k0 = kc*128;
    for (int j=0;j<128;j++) {
        int k = k0 + j;
        float4 g = *(const float4*)(kt + 4*k);
        float u = g.x*f.x + g.y*f.y + g.z*f.z;
        float s,c; sc_frac(u, s, c);
        acc = fmaf(c, SrW[k], fmaf(s, SiW[k], acc));
    }
    wsf[OFF_BPART/4 + kc*NM + m] = acc;
}

// -------- B = -field; init CG residuals r1=B, r2=1 --------
__global__ void k_bfinal(float* __restrict__ wsf) {
    int m = blockIdx.x*256 + threadIdx.x;
    float s = 0.f;
    for (int kc=0;kc<62;kc++) s += wsf[OFF_BPART/4 + kc*NM + m];
    float B = -s;
    wsf[OFF_B/4 + m] = B;
    float* vec = wsf + OFF_VEC/4;
    vec[4096 + m] = B;    // r1
    vec[6144 + m] = 1.f;  // r2
}

// -------- A build: triangular 64x64 tiles, on-the-fly sincos staging --------
__launch_bounds__(256)
__global__ void k_abuild(float* __restrict__ wsf) {
    __shared__ float cwi[32][64], swi[32][64], cjs[32][64], sjs[32][64];
    __shared__ float4 fi[64], fj[64];
    int tid = threadIdx.x;
    int bid = blockIdx.x;
    int bi = (int)((sqrtf(8.f*bid + 1.f) - 1.f)*0.5f);
    while ((bi+1)*(bi+2)/2 <= bid) bi++;
    while (bi*(bi+1)/2 > bid) bi--;
    int bj = bid - bi*(bi+1)/2;

    const int* mlist = (const int*)wsf + OFF_MLIST/4;
    const float* frac = wsf + OFF_FRAC/4;
    const float* ktab = wsf + OFF_KTAB/4;
    float J = wsf[OFF_CONSTS/4 + 10];

    if (tid < 64)        fi[tid]     = *(const float4*)(frac + 4*mlist[bi*64 + tid]);
    else if (tid < 128)  fj[tid-64]  = *(const float4*)(frac + 4*mlist[bj*64 + (tid-64)]);
    __syncthreads();

    int col = tid & 63;
    int kkb = tid >> 6;       // 0..3
    float4 fir = fi[col];
    float4 fjr = fj[col];
    int ty = tid >> 4, tx = tid & 15;
    int ty4 = ty*4, tx4 = tx*4;
    float acc[4][4] = {};

    for (int k0=0; k0<KHP; k0+=32) {
        #pragma unroll
        for (int it=0; it<8; it++) {
            int kk = kkb + it*4;
            float4 kt = *(const float4*)(ktab + 4*(k0+kk));
            float u = kt.x*fir.x + kt.y*fir.y + kt.z*fir.z;
            float s,c; sc_frac(u, s, c);
            cwi[kk][col] = kt.w*c; swi[kk][col] = kt.w*s;
            u = kt.x*fjr.x + kt.y*fjr.y + kt.z*fjr.z;
            sc_frac(u, s, c);
            cjs[kk][col] = c; sjs[kk][col] = s;
        }
        __syncthreads();
        #pragma unroll 4
        for (int kk=0; kk<32; kk++) {
            float4 ac  = *(const float4*)&cwi[kk][ty4];
            float4 as2 = *(const float4*)&swi[kk][ty4];
            float4 bc  = *(const float4*)&cjs[kk][tx4];
            float4 bs  = *(const float4*)&sjs[kk][tx4];
            float aC[4] = {ac.x, ac.y, ac.z, ac.w};
            float aS[4] = {as2.x, as2.y, as2.z, as2.w};
            float bC[4] = {bc.x, bc.y, bc.z, bc.w};
            float bS[4] = {bs.x, bs.y, bs.z, bs.w};
            #pragma unroll
            for (int a=0;a<4;a++)
                #pragma unroll
                for (int b=0;b<4;b++)
                    acc[a][b] = fmaf(aC[a], bC[b], fmaf(aS[a], bS[b], acc[a][b]));
        }
        __syncthreads();
    }

    float* A = wsf + OFF_A/4;
    int gi0 = bi*64 + ty4, gj0 = bj*64 + tx4;
    #pragma unroll
    for (int a=0;a<4;a++) {
        int gi = gi0 + a;
        #pragma unroll
        for (int b=0;b<4;b++) {
            int gj = gj0 + b;
            float v = acc[a][b] + ((gi==gj) ? J : 0.f);
            A[gi*NM + gj] = v;
            A[gj*NM + gi] = v;
        }
    }
}

// -------- software grid barrier (device-scope, generation-based) --------
__device__ __forceinline__ void gbar(int* cnt, int* gen, int target) {
    __syncthreads();
    if (threadIdx.x == 0) {
        __threadfence();  // release prior writes (device scope)
        if (__hip_atomic_fetch_add(cnt, 1, __ATOMIC_ACQ_REL, __HIP_MEMORY_SCOPE_AGENT)
            == NBLK_CG - 1) {
            __hip_atomic_store(cnt, 0, __ATOMIC_RELAXED, __HIP_MEMORY_SCOPE_AGENT);
            __hip_atomic_store(gen, target, __ATOMIC_RELEASE, __HIP_MEMORY_SCOPE_AGENT);
        } else {
            while (__hip_atomic_load(gen, __ATOMIC_ACQUIRE, __HIP_MEMORY_SCOPE_AGENT) < target)
                __builtin_amdgcn_s_sleep(1);
        }
        __threadfence();  // acquire side
    }
    __syncthreads();
}

// -------- persistent CG: all NIT iterations in one dispatch --------
// 256 blocks x 256 threads; block owns rows 8b..8b+7; 32 lanes per row.
// Chronopoulos-Gear: w=A*r, gamma=(r,r), delta=(r,w); one reduction point/iter.
__launch_bounds__(256, 1)
__global__ void k_cg(float* __restrict__ wsf) {
    const float* A = wsf + OFF_A/4;
    float* vec = wsf + OFF_VEC/4;
    float* x1g = vec;          float* x2g = vec + 2048;
    float* r1g = vec + 4096;   float* r2g = vec + 6144;
    float* part = wsf + OFF_PART/4;          // 256 blocks * 4 floats
    int* bar = (int*)wsf + OFF_BAR/4;        // [0]=cnt [1]=gen

    __shared__ float r1s[NM], r2s[NM];
    __shared__ float wS1[8], wS2[8], pS1[8], pS2[8], sS1[8], sS2[8], xS1[8], xS2[8];
    __shared__ float red4[4][4];             // cross-wave float4 reduce scratch

    int tid = threadIdx.x, bid = blockIdx.x;
    int rl = tid >> 5, lane = tid & 31;
    int row = bid*8 + rl;
    const float* Arow = A + (size_t)row*NM;

    float gp1=0.f, ap1=1.f, gp2=0.f, ap2=1.f;   // running CG scalars (all threads)
    int bt = 0;                                  // barrier sequence number

    for (int iter=0; iter<NIT; ++iter) {
        // ---- stage r into LDS (full vectors, float4) ----
        for (int i=tid; i<NM/4; i+=256) {
            ((float4*)r1s)[i] = ((const float4*)r1g)[i];
            ((float4*)r2s)[i] = ((const float4*)r2g)[i];
        }
        __syncthreads();
        // ---- matvec: w = A*r for own 8 rows, 2 RHS ----
        float acc1=0.f, acc2=0.f;
        #pragma unroll 4
        for (int c=lane*4; c<NM; c+=128) {
            float4 a  = *(const float4*)(Arow + c);
            float4 u1 = *(const float4*)(r1s + c);
            float4 u2 = *(const float4*)(r2s + c);
            acc1 += a.x*u1.x + a.y*u1.y + a.z*u1.z + a.w*u1.w;
            acc2 += a.x*u2.x + a.y*u2.y + a.z*u2.z + a.w*u2.w;
        }
        #pragma unroll
        for (int off=1; off<32; off<<=1) {
            acc1 += __shfl_xor(acc1, off);
            acc2 += __shfl_xor(acc2, off);
        }
        if (lane == 0) { wS1[rl] = acc1; wS2[rl] = acc2; }
        __syncthreads();
        // ---- block-local dot partials over own rows ----
        if (tid == 0) {
            float g1=0.f,g2=0.f,d1=0.f,d2=0.f;
            #pragma unroll
            for (int j=0;j<8;j++) {
                float rv1 = r1s[bid*8+j], rv2 = r2s[bid*8+j];
                g1 += rv1*rv1; d1 += rv1*wS1[j];
                g2 += rv2*rv2; d2 += rv2*wS2[j];
            }
            *(float4*)(part + 4*bid) = make_float4(g1,g2,d1,d2);
        }
        gbar(bar, bar+1, ++bt);
        // ---- redundant global dot reduce (deterministic) ----
        float4 pv = ((const float4*)part)[tid];
        #pragma unroll
        for (int off=1; off<64; off<<=1) {
            pv.x += __shfl_xor(pv.x, off);
            pv.y += __shfl_xor(pv.y, off);
            pv.z += __shfl_xor(pv.z, off);
            pv.w += __shfl_xor(pv.w, off);
        }
        if ((tid & 63) == 0) *(float4*)red4[tid>>6] = pv;
        __syncthreads();
        float g1 = red4[0][0]+red4[1][0]+red4[2][0]+red4[3][0];
        float g2 = red4[0][1]+red4[1][1]+red4[2][1]+red4[3][1];
        float d1 = red4[0][2]+red4[1][2]+red4[2][2]+red4[3][2];
        float d2 = red4[0][3]+red4[1][3]+red4[2][3]+red4[3][3];
        // ---- CG scalar recurrences (all threads, identical) ----
        float b1, a1, b2, a2;
        if (iter == 0) { b1=0.f; a1=g1/d1; b2=0.f; a2=g2/d2; }
        else {
            b1 = g1/gp1; a1 = g1/(d1 - b1*g1/ap1);
            b2 = g2/gp2; a2 = g2/(d2 - b2*g2/ap2);
        }
        gp1=g1; ap1=a1; gp2=g2; ap2=a2;
        // ---- vector updates for own rows (lane 0 of each row) ----
        if (lane == 0) {
            float rv1 = r1s[row], wv1 = wS1[rl];
            float pv1 = (iter==0) ? rv1 : fmaf(b1, pS1[rl], rv1);
            float sv1 = (iter==0) ? wv1 : fmaf(b1, sS1[rl], wv1);
            pS1[rl]=pv1; sS1[rl]=sv1;
            xS1[rl] = (iter==0) ? a1*pv1 : fmaf(a1, pv1, xS1[rl]);
            r1g[row] = fmaf(-a1, sv1, rv1);

            float rv2 = r2s[row], wv2 = wS2[rl];
            float pv2 = (iter==0) ? rv2 : fmaf(b2, pS2[rl], rv2);
            float sv2 = (iter==0) ? wv2 : fmaf(b2, sS2[rl], wv2);
            pS2[rl]=pv2; sS2[rl]=sv2;
            xS2[rl] = (iter==0) ? a2*pv2 : fmaf(a2, pv2, xS2[rl]);
            r2g[row] = fmaf(-a2, sv2, rv2);
        }
        gbar(bar, bar+1, ++bt);
    }
    // ---- write solutions ----
    if (lane == 0) { x1g[row] = xS1[rl]; x2g[row] = xS2[rl]; }
}

// -------- lambda = sum(x1)/sum(x2) --------
__global__ void k_sum(float* __restrict__ wsf) {
    int tid = threadIdx.x;
    float* vec = wsf + OFF_VEC/4;
    float s1=0.f, s2=0.f;
    for (int i=tid; i<NM; i+=256) { s1 += vec[i]; s2 += vec[2048+i]; }
    __shared__ float a[256], b[256];
    a[tid]=s1; b[tid]=s2; __syncthreads();
    for (int off=128; off>0; off>>=1) {
        if (tid<off) { a[tid]+=a[tid+off]; b[tid]+=b[tid+off]; }
        __syncthreads();
    }
    if (tid==0) wsf[OFF_SUMS/4 + 2] = a[0]/b[0];
}

// -------- assemble output --------
__global__ void k_out(const float* __restrict__ q, const int* __restrict__ an,
                      const float* __restrict__ wsf, float* __restrict__ out) {
    int i = blockIdx.x*256 + threadIdx.x;
    if (i >= NA) return;
    if (an[i]==METAL_Z) {
        int p = ((const int*)wsf)[OFF_POSOF/4 + i];
        float lam = wsf[OFF_SUMS/4 + 2];
        const float* vec = wsf + OFF_VEC/4;
        out[i] = vec[p] - lam*vec[2048 + p];
    } else {
        out[i] = q[i];
    }
}

extern "C" void kernel_launch(void* const* d_in, const int* in_sizes, int n_in,
                              void* d_out, int out_size, void* d_ws, size_t ws_size,
                              hipStream_t stream) {
    (void)in_sizes; (void)n_in; (void)out_size; (void)ws_size;
    const float* pos  = (const float*)d_in[0];
    const float* cell = (const float*)d_in[1];
    const float* q    = (const float*)d_in[2];
    const float* Jraw = (const float*)d_in[3];
    const int*   an   = (const int*)d_in[4];
    float* wsf = (float*)d_ws;
    float* out = (float*)d_out;

    k_setup<<<1, 256, 0, stream>>>(pos, cell, Jraw, an, wsf);
    k_ktab<<<KHP/256, 256, 0, stream>>>(wsf);
    k_srsi<<<KHP, 256, 0, stream>>>(q, an, wsf);
    k_field<<<dim3(62, 8), 256, 0, stream>>>(wsf);
    k_bfinal<<<NM/256, 256, 0, stream>>>(wsf);
    k_abuild<<<528, 256, 0, stream>>>(wsf);
    k_cg<<<NBLK_CG, 256, 0, stream>>>(wsf);
    k_sum<<<1, 256, 0, stream>>>(wsf);
    k_out<<<NA/256, 256, 0, stream>>>(q, an, wsf, out);
}

// Round 4
// 2818.593 us; speedup vs baseline: 3.2224x; 3.2224x over previous
//
#include <hip/hip_runtime.h>
#include <math.h>

// MetalWallQEQ: reciprocal-space Ewald QEQ for metal-wall charges.
// Round 4: (a) persistent CG with cheap flag barrier (relaxed polling, w-row
// exchange only, replicated scalar state -> 1 barrier/iter, no L2-invalidate
// storms); (b) A-build K-split x4 + atomicAdd (load balance) + native v_sin/v_cos.

#define NA 4096
#define NM 2048
#define METAL_Z 79
#define KH 7812          // (25^3-1)/2 half k-points
#define KHP 7936         // padded to 62*128 (pad entries have w=0)
#define KQ  (KHP/4)      // 1984 k per abuild z-slice
#define NIT 150          // fixed CG iterations (graph-friendly)
#define NBLK_CG 256      // persistent CG grid: 1 block/CU, co-resident
#define TWO_PI 6.283185307179586f

// ---- workspace byte offsets (total ~17.7 MB) ----
#define OFF_CONSTS 0        // [0..8]=invT(cell) row-major, [9]=pref=4pi/V, [10]=J
#define OFF_SUMS   256      // [2]=lambda
#define OFF_FLAGS  512      // 256 ints: CG barrier flags (zeroed per call)
#define OFF_KTAB   4096     // KHP * {gx,gy,gz,w} floats
#define OFF_FRAC   131072   // NA * {fx,fy,fz,0} fractional coords
#define OFF_MLIST  196608   // NM ints: metal position -> atom index
#define OFF_POSOF  204800   // NA ints: atom -> metal position (metal only)
#define OFF_SRW    221184   // KHP floats: w*Re S(k)
#define OFF_SIW    252928   // KHP floats: w*Im S(k)
#define OFF_BPART  284672   // 62*NM floats: field partials
#define OFF_B      792576   // NM floats
#define OFF_VEC    800768   // x1,x2,r1,r2 (each NM floats)
#define OFF_WBUF   833536   // 2 parity * 2 rhs * NM floats (32KB) CG w exchange
#define OFF_A      917504   // NM*NM floats (A + J on diagonal)

__device__ __forceinline__ void sc_frac(float u, float& s, float& c) {
    // u is phase in REVOLUTIONS; v_sin/v_cos take revolutions directly.
    float t = u - floorf(u);
    s = __builtin_amdgcn_sinf(t);
    c = __builtin_amdgcn_cosf(t);
}

// -------- setup: cell inverse, fractional coords, metal scan, zero flags --------
__global__ void k_setup(const float* __restrict__ pos, const float* __restrict__ cell,
                        const float* __restrict__ Jraw, const int* __restrict__ an,
                        float* __restrict__ wsf) {
    int tid = threadIdx.x;
    __shared__ float sM[9];
    __shared__ int sc[256];
    if (tid == 0) {
        float c00=cell[0],c01=cell[1],c02=cell[2];
        float c10=cell[3],c11=cell[4],c12=cell[5];
        float c20=cell[6],c21=cell[7],c22=cell[8];
        float det = c00*(c11*c22-c12*c21) - c01*(c10*c22-c12*c20) + c02*(c10*c21-c11*c20);
        float i00 =  (c11*c22 - c12*c21)/det;
        float i01 = -(c01*c22 - c02*c21)/det;
        float i02 =  (c01*c12 - c02*c11)/det;
        float i10 = -(c10*c22 - c12*c20)/det;
        float i11 =  (c00*c22 - c02*c20)/det;
        float i12 = -(c00*c12 - c02*c10)/det;
        float i20 =  (c10*c21 - c11*c20)/det;
        float i21 = -(c00*c21 - c01*c20)/det;
        float i22 =  (c00*c11 - c01*c10)/det;
        sM[0]=i00; sM[1]=i10; sM[2]=i20;
        sM[3]=i01; sM[4]=i11; sM[5]=i21;
        sM[6]=i02; sM[7]=i12; sM[8]=i22;
        float vol = fabsf(det);
        for (int m=0;m<9;m++) wsf[OFF_CONSTS/4 + m] = sM[m];
        wsf[OFF_CONSTS/4 + 9]  = 12.566370614359172f / vol;   // 4pi/V
        wsf[OFF_CONSTS/4 + 10] = Jraw[0]*Jraw[0];
    }
    __syncthreads();
    float M0=sM[0],M1=sM[1],M2=sM[2],M3=sM[3],M4=sM[4],M5=sM[5],M6=sM[6],M7=sM[7],M8=sM[8];
    for (int i=tid; i<NA; i+=256) {
        float x=pos[3*i], y=pos[3*i+1], z=pos[3*i+2];
        wsf[OFF_FRAC/4 + 4*i+0] = M0*x + M1*y + M2*z;
        wsf[OFF_FRAC/4 + 4*i+1] = M3*x + M4*y + M5*z;
        wsf[OFF_FRAC/4 + 4*i+2] = M6*x + M7*y + M8*z;
        wsf[OFF_FRAC/4 + 4*i+3] = 0.f;
    }
    ((int*)wsf)[OFF_FLAGS/4 + tid] = 0;       // CG barrier flags
    if (tid < 4) wsf[OFF_SUMS/4 + tid] = 0.f;
    // metal prefix scan (deterministic ordering == np.where order)
    int cnt = 0;
    int base_i = tid*16;
    for (int j=0;j<16;j++) cnt += (an[base_i+j]==METAL_Z) ? 1 : 0;
    sc[tid] = cnt; __syncthreads();
    for (int off=1; off<256; off<<=1) {
        int v = (tid>=off) ? sc[tid-off] : 0;
        __syncthreads();
        sc[tid] += v;
        __syncthreads();
    }
    int base = sc[tid] - cnt;
    int* mlist = (int*)wsf + OFF_MLIST/4;
    int* posof = (int*)wsf + OFF_POSOF/4;
    for (int j=0;j<16;j++) {
        int i = base_i + j;
        if (an[i]==METAL_Z) { mlist[base] = i; posof[i] = base; base++; }
    }
}

// -------- zero A, J on diagonal (abuild accumulates with atomicAdd) --------
__global__ void k_azero(float* __restrict__ wsf) {
    float J = wsf[OFF_CONSTS/4 + 10];
    float4* A4 = (float4*)(wsf + OFF_A/4);
    const int n4 = NM*NM/4;
    for (int i = blockIdx.x*256 + threadIdx.x; i < n4; i += gridDim.x*256) {
        float4 v = make_float4(0.f,0.f,0.f,0.f);
        int e = i*4;
        #pragma unroll
        for (int j=0;j<4;j++) if ((e+j) % (NM+1) == 0) ((float*)&v)[j] = J;
        A4[i] = v;
    }
}

// -------- k-table: integer triple + weight w = 2*pref*exp(-k2/2)/k2 --------
__global__ void k_ktab(float* __restrict__ wsf) {
    int k = blockIdx.x*256 + threadIdx.x;
    if (k >= KHP) return;
    float4 out;
    if (k < KH) {
        int gx = k/625 - 12;
        int rem = k%625;
        int gy = rem/25 - 12;
        int gz = rem%25 - 12;
        const float* M = wsf + OFF_CONSTS/4;
        float pref = M[9];
        float kx = TWO_PI*(gx*M[0] + gy*M[3] + gz*M[6]);
        float ky = TWO_PI*(gx*M[1] + gy*M[4] + gz*M[7]);
        float kz = TWO_PI*(gx*M[2] + gy*M[5] + gz*M[8]);
        float k2 = kx*kx + ky*ky + kz*kz;
        float kfac = __expf(-0.5f*k2) / k2;
        out = make_float4((float)gx, (float)gy, (float)gz, 2.f*pref*kfac);
    } else {
        out = make_float4(0.f, 0.f, 0.f, 0.f);
    }
    *(float4*)(wsf + OFF_KTAB/4 + 4*k) = out;
}

// -------- structure factors over electrolyte charges (metal q := 0) --------
__global__ void k_srsi(const float* __restrict__ q, const int* __restrict__ an,
                       float* __restrict__ wsf) {
    int k = blockIdx.x;
    int tid = threadIdx.x;
    float4 kt = *(const float4*)(wsf + OFF_KTAB/4 + 4*k);
    const float* frac = wsf + OFF_FRAC/4;
    float aR=0.f, aI=0.f;
    for (int i=tid; i<NA; i+=256) {
        float qa = (an[i]==METAL_Z) ? 0.f : q[i];
        float4 f = *(const float4*)(frac + 4*i);
        float u = kt.x*f.x + kt.y*f.y + kt.z*f.z;
        float s,c; sc_frac(u, s, c);
        aR += qa*c; aI += qa*s;
    }
    __shared__ float sR[256], sI[256];
    sR[tid]=aR; sI[tid]=aI; __syncthreads();
    for (int off=128; off>0; off>>=1) {
        if (tid<off) { sR[tid]+=sR[tid+off]; sI[tid]+=sI[tid+off]; }
        __syncthreads();
    }
    if (tid==0) {
        wsf[OFF_SRW/4 + k] = kt.w * sR[0];
        wsf[OFF_SIW/4 + k] = kt.w * sI[0];
    }
}

// -------- field at metal atoms (partial over k-chunks) --------
__global__ void k_field(float* __restrict__ wsf) {
    int kc = blockIdx.x;
    int m = blockIdx.y*256 + threadIdx.x;
    int atom = ((const int*)wsf)[OFF_MLIST/4 + m];
    float4 f = *(const float4*)(wsf + OFF_FRAC/4 + 4*atom);
    const float* kt = wsf + OFF_KTAB/4;
    const float* SrW = wsf + OFF_SRW/4;
    const float* SiW = wsf + OFF_SIW/4;
    float acc = 0.f;
    int k0 = kc*128;
    for (int j=0;j<128;j++) {
        int k = k0 + j;
        float4 g = *(const float4*)(kt + 4*k);
        float u = g.x*f.x + g.y*f.y + g.z*f.z;
        float s,c; sc_frac(u, s, c);
        acc = fmaf(c, SrW[k], fmaf(s, SiW[k], acc));
    }
    wsf[OFF_BPART/4 + kc*NM + m] = acc;
}

// -------- B = -field; init CG residuals r1=B, r2=1 --------
__global__ void k_bfinal(float* __restrict__ wsf) {
    int m = blockIdx.x*256 + threadIdx.x;
    float s = 0.f;
    for (int kc=0;kc<62;kc++) s += wsf[OFF_BPART/4 + kc*NM + m];
    float B = -s;
    wsf[OFF_B/4 + m] = B;
    float* vec = wsf + OFF_VEC/4;
    vec[4096 + m] = B;    // r1
    vec[6144 + m] = 1.f;  // r2
}

// -------- A build: triangular 64x64 tiles, K-split x4 (blockIdx.y), atomicAdd --------
__launch_bounds__(256)
__global__ void k_abuild(float* __restrict__ wsf) {
    __shared__ float cwi[32][64], swi[32][64], cjs[32][64], sjs[32][64];
    __shared__ float4 fi[64], fj[64];
    int tid = threadIdx.x;
    int bid = blockIdx.x;
    int kq  = blockIdx.y;
    int bi = (int)((sqrtf(8.f*bid + 1.f) - 1.f)*0.5f);
    while ((bi+1)*(bi+2)/2 <= bid) bi++;
    while (bi*(bi+1)/2 > bid) bi--;
    int bj = bid - bi*(bi+1)/2;

    const int* mlist = (const int*)wsf + OFF_MLIST/4;
    const float* frac = wsf + OFF_FRAC/4;
    const float* ktab = wsf + OFF_KTAB/4;

    if (tid < 64)        fi[tid]     = *(const float4*)(frac + 4*mlist[bi*64 + tid]);
    else if (tid < 128)  fj[tid-64]  = *(const float4*)(frac + 4*mlist[bj*64 + (tid-64)]);
    __syncthreads();

    int col = tid & 63;
    int kkb = tid >> 6;       // 0..3
    float4 fir = fi[col];
    float4 fjr = fj[col];
    int ty = tid >> 4, tx = tid & 15;
    int ty4 = ty*4, tx4 = tx*4;
    float acc[4][4] = {};

    for (int k0=kq*KQ; k0<(kq+1)*KQ; k0+=32) {
        #pragma unroll
        for (int it=0; it<8; it++) {
            int kk = kkb + it*4;
            float4 kt = *(const float4*)(ktab + 4*(k0+kk));
            float u = kt.x*fir.x + kt.y*fir.y + kt.z*fir.z;
            float s,c; sc_frac(u, s, c);
            cwi[kk][col] = kt.w*c; swi[kk][col] = kt.w*s;
            u = kt.x*fjr.x + kt.y*fjr.y + kt.z*fjr.z;
            sc_frac(u, s, c);
            cjs[kk][col] = c; sjs[kk][col] = s;
        }
        __syncthreads();
        #pragma unroll 4
        for (int kk=0; kk<32; kk++) {
            float4 ac  = *(const float4*)&cwi[kk][ty4];
            float4 as2 = *(const float4*)&swi[kk][ty4];
            float4 bc  = *(const float4*)&cjs[kk][tx4];
            float4 bs  = *(const float4*)&sjs[kk][tx4];
            float aC[4] = {ac.x, ac.y, ac.z, ac.w};
            float aS[4] = {as2.x, as2.y, as2.z, as2.w};
            float bC[4] = {bc.x, bc.y, bc.z, bc.w};
            float bS[4] = {bs.x, bs.y, bs.z, bs.w};
            #pragma unroll
            for (int a=0;a<4;a++)
                #pragma unroll
                for (int b=0;b<4;b++)
                    acc[a][b] = fmaf(aC[a], bC[b], fmaf(aS[a], bS[b], acc[a][b]));
        }
        __syncthreads();
    }

    float* A = wsf + OFF_A/4;
    int gi0 = bi*64 + ty4, gj0 = bj*64 + tx4;
    if (bi == bj) {
        #pragma unroll
        for (int a=0;a<4;a++)
            #pragma unroll
            for (int b=0;b<4;b++)
                atomicAdd(&A[(size_t)(gi0+a)*NM + gj0+b], acc[a][b]);
    } else {
        #pragma unroll
        for (int a=0;a<4;a++)
            #pragma unroll
            for (int b=0;b<4;b++) {
                float v = acc[a][b];
                atomicAdd(&A[(size_t)(gi0+a)*NM + gj0+b], v);
                atomicAdd(&A[(size_t)(gj0+b)*NM + gi0+a], v);
            }
    }
}

// -------- persistent CG: 1 flag-barrier/iter, w-row exchange only --------
// 256 blocks x 256 threads. Block owns rows [bid*8, bid*8+8) for the matvec
// (32 lanes/row). Thread owns elements [tid*8, tid*8+8) of the full vectors.
// Full r (LDS) and s (regs) are replicated bit-identically in every block:
// they evolve from the globally shared w and identical deterministic dots.
__launch_bounds__(256, 1)
__global__ void k_cg(float* __restrict__ wsf) {
    const float* A = wsf + OFF_A/4;
    float* vec = wsf + OFF_VEC/4;
    float* x1g = vec;              float* x2g = vec + 2048;
    const float* r1g = vec + 4096; const float* r2g = vec + 6144;
    int* flags = (int*)wsf + OFF_FLAGS/4;
    float* wbuf = wsf + OFF_WBUF/4;      // [parity][rhs][NM]

    __shared__ float r1s[NM], r2s[NM];
    __shared__ float red[16];            // 4 waves x {g1,d1,g2,d2}

    int tid = threadIdx.x, bid = blockIdx.x;
    int rl = tid >> 5, lane = tid & 31;
    int row = bid*8 + rl;
    const float* Arow = A + (size_t)row*NM;
    int e0 = tid*8;

    for (int i=tid; i<NM/4; i+=256) {
        ((float4*)r1s)[i] = ((const float4*)r1g)[i];
        ((float4*)r2s)[i] = ((const float4*)r2g)[i];
    }
    __syncthreads();

    float s1r[8], s2r[8];
    float p1r=0.f, p2r=0.f, x1r=0.f, x2r=0.f;    // own-row p/x (tid<8 only)
    float gp1=1.f, ap1=1.f, gp2=1.f, ap2=1.f;

    for (int iter=0; iter<NIT; ++iter) {
        // ---- w_own = A_own x r (2 RHS), 32 lanes per row ----
        float acc1=0.f, acc2=0.f;
        #pragma unroll 8
        for (int c=lane*4; c<NM; c+=128) {
            float4 a  = *(const float4*)(Arow + c);
            float4 u1 = *(const float4*)(r1s + c);
            float4 u2 = *(const float4*)(r2s + c);
            acc1 += a.x*u1.x + a.y*u1.y + a.z*u1.z + a.w*u1.w;
            acc2 += a.x*u2.x + a.y*u2.y + a.z*u2.z + a.w*u2.w;
        }
        #pragma unroll
        for (int off=1; off<32; off<<=1) {
            acc1 += __shfl_xor(acc1, off);
            acc2 += __shfl_xor(acc2, off);
        }
        float* wb = wbuf + (iter&1)*4096;
        if (lane == 0) {
            __hip_atomic_store(wb + row,        acc1, __ATOMIC_RELAXED, __HIP_MEMORY_SCOPE_AGENT);
            __hip_atomic_store(wb + 2048 + row, acc2, __ATOMIC_RELAXED, __HIP_MEMORY_SCOPE_AGENT);
        }
        __syncthreads();
        // ---- flag barrier: release own flag, wave0 relaxed-polls all 256 ----
        if (tid == 0)
            __hip_atomic_store(&flags[bid], iter+1, __ATOMIC_RELEASE, __HIP_MEMORY_SCOPE_AGENT);
        if (tid < 64) {
            for (;;) {
                int ok = 1;
                #pragma unroll
                for (int j=0;j<4;j++) {
                    int v = __hip_atomic_load(&flags[tid*4+j], __ATOMIC_RELAXED, __HIP_MEMORY_SCOPE_AGENT);
                    ok &= (v >= iter+1);
                }
                if (__all(ok)) break;
                __builtin_amdgcn_s_sleep(1);
            }
        }
        __syncthreads();
        // ---- gather own w slice (coherent L3 reads, no cache invalidates) ----
        float w1r[8], w2r[8];
        #pragma unroll
        for (int j=0;j<8;j++) {
            w1r[j] = __hip_atomic_load(wb + e0 + j,        __ATOMIC_RELAXED, __HIP_MEMORY_SCOPE_AGENT);
            w2r[j] = __hip_atomic_load(wb + 2048 + e0 + j, __ATOMIC_RELAXED, __HIP_MEMORY_SCOPE_AGENT);
        }
        // ---- dots gamma=(r,r), delta=(r,w): slice -> wave -> LDS (deterministic) ----
        float g1=0.f,d1=0.f,g2=0.f,d2=0.f;
        #pragma unroll
        for (int j=0;j<8;j++) {
            float rv1=r1s[e0+j], rv2=r2s[e0+j];
            g1 = fmaf(rv1,rv1,g1); d1 = fmaf(rv1,w1r[j],d1);
            g2 = fmaf(rv2,rv2,g2); d2 = fmaf(rv2,w2r[j],d2);
        }
        #pragma unroll
        for (int off=1; off<64; off<<=1) {
            g1 += __shfl_xor(g1,off); d1 += __shfl_xor(d1,off);
            g2 += __shfl_xor(g2,off); d2 += __shfl_xor(d2,off);
        }
        if ((tid&63)==0) { int w=tid>>6; red[w*4+0]=g1; red[w*4+1]=d1; red[w*4+2]=g2; red[w*4+3]=d2; }
        __syncthreads();
        g1 = red[0]+red[4]+red[8]+red[12];
        d1 = red[1]+red[5]+red[9]+red[13];
        g2 = red[2]+red[6]+red[10]+red[14];
        d2 = red[3]+red[7]+red[11]+red[15];
        // ---- identical scalar recurrences in every thread/block ----
        float b1,a1,b2,a2;
        if (iter == 0) { b1=0.f; a1=g1/d1; b2=0.f; a2=g2/d2; }
        else {
            b1 = g1/gp1; a1 = g1/(d1 - b1*g1/ap1);
            b2 = g2/gp2; a2 = g2/(d2 - b2*g2/ap2);
        }
        gp1=g1; ap1=a1; gp2=g2; ap2=a2;
        // ---- p/x for own rows (read old r before slice update) ----
        if (tid < 8) {
            float rv1 = r1s[bid*8+tid], rv2 = r2s[bid*8+tid];
            p1r = (iter==0) ? rv1 : fmaf(b1, p1r, rv1);
            p2r = (iter==0) ? rv2 : fmaf(b2, p2r, rv2);
            x1r = (iter==0) ? a1*p1r : fmaf(a1, p1r, x1r);
            x2r = (iter==0) ? a2*p2r : fmaf(a2, p2r, x2r);
        }
        __syncthreads();
        // ---- s (regs) and r (LDS) slice updates ----
        #pragma unroll
        for (int j=0;j<8;j++) {
            float sv1 = (iter==0) ? w1r[j] : fmaf(b1, s1r[j], w1r[j]);
            float sv2 = (iter==0) ? w2r[j] : fmaf(b2, s2r[j], w2r[j]);
            s1r[j]=sv1; s2r[j]=sv2;
            r1s[e0+j] = fmaf(-a1, sv1, r1s[e0+j]);
            r2s[e0+j] = fmaf(-a2, sv2, r2s[e0+j]);
        }
        __syncthreads();
    }
    if (tid < 8) { x1g[bid*8+tid] = x1r; x2g[bid*8+tid] = x2r; }
}

// -------- lambda = sum(x1)/sum(x2) --------
__global__ void k_sum(float* __restrict__ wsf) {
    int tid = threadIdx.x;
    float* vec = wsf + OFF_VEC/4;
    float s1=0.f, s2=0.f;
    for (int i=tid; i<NM; i+=256) { s1 += vec[i]; s2 += vec[2048+i]; }
    __shared__ float a[256], b[256];
    a[tid]=s1; b[tid]=s2; __syncthreads();
    for (int off=128; off>0; off>>=1) {
        if (tid<off) { a[tid]+=a[tid+off]; b[tid]+=b[tid+off]; }
        __syncthreads();
    }
    if (tid==0) wsf[OFF_SUMS/4 + 2] = a[0]/b[0];
}

// -------- assemble output --------
__global__ void k_out(const float* __restrict__ q, const int* __restrict__ an,
                      const float* __restrict__ wsf, float* __restrict__ out) {
    int i = blockIdx.x*256 + threadIdx.x;
    if (i >= NA) return;
    if (an[i]==METAL_Z) {
        int p = ((const int*)wsf)[OFF_POSOF/4 + i];
        float lam = wsf[OFF_SUMS/4 + 2];
        const float* vec = wsf + OFF_VEC/4;
        out[i] = vec[p] - lam*vec[2048 + p];
    } else {
        out[i] = q[i];
    }
}

extern "C" void kernel_launch(void* const* d_in, const int* in_sizes, int n_in,
                              void* d_out, int out_size, void* d_ws, size_t ws_size,
                              hipStream_t stream) {
    (void)in_sizes; (void)n_in; (void)out_size; (void)ws_size;
    const float* pos  = (const float*)d_in[0];
    const float* cell = (const float*)d_in[1];
    const float* q    = (const float*)d_in[2];
    const float* Jraw = (const float*)d_in[3];
    const int*   an   = (const int*)d_in[4];
    float* wsf = (float*)d_ws;
    float* out = (float*)d_out;

    k_setup<<<1, 256, 0, stream>>>(pos, cell, Jraw, an, wsf);
    k_azero<<<1024, 256, 0, stream>>>(wsf);
    k_ktab<<<KHP/256, 256, 0, stream>>>(wsf);
    k_srsi<<<KHP, 256, 0, stream>>>(q, an, wsf);
    k_field<<<dim3(62, 8), 256, 0, stream>>>(wsf);
    k_bfinal<<<NM/256, 256, 0, stream>>>(wsf);
    k_abuild<<<dim3(528, 4), 256, 0, stream>>>(wsf);
    k_cg<<<NBLK_CG, 256, 0, stream>>>(wsf);
    k_sum<<<1, 256, 0, stream>>>(wsf);
    k_out<<<NA/256, 256, 0, stream>>>(q, an, wsf, out);
}

// Round 5
// 2592.008 us; speedup vs baseline: 3.5041x; 1.0874x over previous
//
#include <hip/hip_runtime.h>
#include <math.h>

// MetalWallQEQ: reciprocal-space Ewald QEQ for metal-wall charges.
// Round 5: CG comms fix — float4-chunk element mapping (kills 16-way LDS bank
// conflicts), 8B packed atomic gathers/polls (8x fewer device-scope
// transactions). Structure (persistent CG, flag barrier) unchanged.

#define NA 4096
#define NM 2048
#define METAL_Z 79
#define KH 7812          // (25^3-1)/2 half k-points
#define KHP 7936         // padded to 62*128 (pad entries have w=0)
#define KQ  (KHP/4)      // 1984 k per abuild z-slice
#define NIT 150          // fixed CG iterations (graph-friendly)
#define NBLK_CG 256      // persistent CG grid: 1 block/CU, co-resident
#define TWO_PI 6.283185307179586f

// ---- workspace byte offsets (total ~17.7 MB) ----
#define OFF_CONSTS 0        // [0..8]=invT(cell) row-major, [9]=pref=4pi/V, [10]=J
#define OFF_SUMS   256      // [2]=lambda
#define OFF_FLAGS  512      // 256 ints: CG barrier flags (zeroed per call)
#define OFF_KTAB   4096     // KHP * {gx,gy,gz,w} floats
#define OFF_FRAC   131072   // NA * {fx,fy,fz,0} fractional coords
#define OFF_MLIST  196608   // NM ints: metal position -> atom index
#define OFF_POSOF  204800   // NA ints: atom -> metal position (metal only)
#define OFF_SRW    221184   // KHP floats: w*Re S(k)
#define OFF_SIW    252928   // KHP floats: w*Im S(k)
#define OFF_BPART  284672   // 62*NM floats: field partials
#define OFF_B      792576   // NM floats
#define OFF_VEC    800768   // x1,x2,r1,r2 (each NM floats)
#define OFF_WBUF   833536   // 2 parity * 2 rhs * NM floats (32KB) CG w exchange
#define OFF_A      917504   // NM*NM floats (A + J on diagonal)

__device__ __forceinline__ void sc_frac(float u, float& s, float& c) {
    // u is phase in REVOLUTIONS; v_sin/v_cos take revolutions directly.
    float t = u - floorf(u);
    s = __builtin_amdgcn_sinf(t);
    c = __builtin_amdgcn_cosf(t);
}

__device__ __forceinline__ float2 ld_f2_agent(const float* p) {
    unsigned long long v = __hip_atomic_load((unsigned long long*)p,
        __ATOMIC_RELAXED, __HIP_MEMORY_SCOPE_AGENT);
    union { unsigned long long u; float2 f; } cv; cv.u = v; return cv.f;
}

// -------- setup: cell inverse, fractional coords, metal scan, zero flags --------
__global__ void k_setup(const float* __restrict__ pos, const float* __restrict__ cell,
                        const float* __restrict__ Jraw, const int* __restrict__ an,
                        float* __restrict__ wsf) {
    int tid = threadIdx.x;
    __shared__ float sM[9];
    __shared__ int sc[256];
    if (tid == 0) {
        float c00=cell[0],c01=cell[1],c02=cell[2];
        float c10=cell[3],c11=cell[4],c12=cell[5];
        float c20=cell[6],c21=cell[7],c22=cell[8];
        float det = c00*(c11*c22-c12*c21) - c01*(c10*c22-c12*c20) + c02*(c10*c21-c11*c20);
        float i00 =  (c11*c22 - c12*c21)/det;
        float i01 = -(c01*c22 - c02*c21)/det;
        float i02 =  (c01*c12 - c02*c11)/det;
        float i10 = -(c10*c22 - c12*c20)/det;
        float i11 =  (c00*c22 - c02*c20)/det;
        float i12 = -(c00*c12 - c02*c10)/det;
        float i20 =  (c10*c21 - c11*c20)/det;
        float i21 = -(c00*c21 - c01*c20)/det;
        float i22 =  (c00*c11 - c01*c10)/det;
        sM[0]=i00; sM[1]=i10; sM[2]=i20;
        sM[3]=i01; sM[4]=i11; sM[5]=i21;
        sM[6]=i02; sM[7]=i12; sM[8]=i22;
        float vol = fabsf(det);
        for (int m=0;m<9;m++) wsf[OFF_CONSTS/4 + m] = sM[m];
        wsf[OFF_CONSTS/4 + 9]  = 12.566370614359172f / vol;   // 4pi/V
        wsf[OFF_CONSTS/4 + 10] = Jraw[0]*Jraw[0];
    }
    __syncthreads();
    float M0=sM[0],M1=sM[1],M2=sM[2],M3=sM[3],M4=sM[4],M5=sM[5],M6=sM[6],M7=sM[7],M8=sM[8];
    for (int i=tid; i<NA; i+=256) {
        float x=pos[3*i], y=pos[3*i+1], z=pos[3*i+2];
        wsf[OFF_FRAC/4 + 4*i+0] = M0*x + M1*y + M2*z;
        wsf[OFF_FRAC/4 + 4*i+1] = M3*x + M4*y + M5*z;
        wsf[OFF_FRAC/4 + 4*i+2] = M6*x + M7*y + M8*z;
        wsf[OFF_FRAC/4 + 4*i+3] = 0.f;
    }
    ((int*)wsf)[OFF_FLAGS/4 + tid] = 0;       // CG barrier flags
    if (tid < 4) wsf[OFF_SUMS/4 + tid] = 0.f;
    // metal prefix scan (deterministic ordering == np.where order)
    int cnt = 0;
    int base_i = tid*16;
    for (int j=0;j<16;j++) cnt += (an[base_i+j]==METAL_Z) ? 1 : 0;
    sc[tid] = cnt; __syncthreads();
    for (int off=1; off<256; off<<=1) {
        int v = (tid>=off) ? sc[tid-off] : 0;
        __syncthreads();
        sc[tid] += v;
        __syncthreads();
    }
    int base = sc[tid] - cnt;
    int* mlist = (int*)wsf + OFF_MLIST/4;
    int* posof = (int*)wsf + OFF_POSOF/4;
    for (int j=0;j<16;j++) {
        int i = base_i + j;
        if (an[i]==METAL_Z) { mlist[base] = i; posof[i] = base; base++; }
    }
}

// -------- zero A, J on diagonal (abuild accumulates with atomicAdd) --------
__global__ void k_azero(float* __restrict__ wsf) {
    float J = wsf[OFF_CONSTS/4 + 10];
    float4* A4 = (float4*)(wsf + OFF_A/4);
    const int n4 = NM*NM/4;
    for (int i = blockIdx.x*256 + threadIdx.x; i < n4; i += gridDim.x*256) {
        float4 v = make_float4(0.f,0.f,0.f,0.f);
        int e = i*4;
        #pragma unroll
        for (int j=0;j<4;j++) if ((e+j) % (NM+1) == 0) ((float*)&v)[j] = J;
        A4[i] = v;
    }
}

// -------- k-table: integer triple + weight w = 2*pref*exp(-k2/2)/k2 --------
__global__ void k_ktab(float* __restrict__ wsf) {
    int k = blockIdx.x*256 + threadIdx.x;
    if (k >= KHP) return;
    float4 out;
    if (k < KH) {
        int gx = k/625 - 12;
        int rem = k%625;
        int gy = rem/25 - 12;
        int gz = rem%25 - 12;
        const float* M = wsf + OFF_CONSTS/4;
        float pref = M[9];
        float kx = TWO_PI*(gx*M[0] + gy*M[3] + gz*M[6]);
        float ky = TWO_PI*(gx*M[1] + gy*M[4] + gz*M[7]);
        float kz = TWO_PI*(gx*M[2] + gy*M[5] + gz*M[8]);
        float k2 = kx*kx + ky*ky + kz*kz;
        float kfac = __expf(-0.5f*k2) / k2;
        out = make_float4((float)gx, (float)gy, (float)gz, 2.f*pref*kfac);
    } else {
        out = make_float4(0.f, 0.f, 0.f, 0.f);
    }
    *(float4*)(wsf + OFF_KTAB/4 + 4*k) = out;
}

// -------- structure factors over electrolyte charges (metal q := 0) --------
__global__ void k_srsi(const float* __restrict__ q, const int* __restrict__ an,
                       float* __restrict__ wsf) {
    int k = blockIdx.x;
    int tid = threadIdx.x;
    float4 kt = *(const float4*)(wsf + OFF_KTAB/4 + 4*k);
    const float* frac = wsf + OFF_FRAC/4;
    float aR=0.f, aI=0.f;
    for (int i=tid; i<NA; i+=256) {
        float qa = (an[i]==METAL_Z) ? 0.f : q[i];
        float4 f = *(const float4*)(frac + 4*i);
        float u = kt.x*f.x + kt.y*f.y + kt.z*f.z;
        float s,c; sc_frac(u, s, c);
        aR += qa*c; aI += qa*s;
    }
    __shared__ float sR[256], sI[256];
    sR[tid]=aR; sI[tid]=aI; __syncthreads();
    for (int off=128; off>0; off>>=1) {
        if (tid<off) { sR[tid]+=sR[tid+off]; sI[tid]+=sI[tid+off]; }
        __syncthreads();
    }
    if (tid==0) {
        wsf[OFF_SRW/4 + k] = kt.w * sR[0];
        wsf[OFF_SIW/4 + k] = kt.w * sI[0];
    }
}

// -------- field at metal atoms (partial over k-chunks) --------
__global__ void k_field(float* __restrict__ wsf) {
    int kc = blockIdx.x;
    int m = blockIdx.y*256 + threadIdx.x;
    int atom = ((const int*)wsf)[OFF_MLIST/4 + m];
    float4 f = *(const float4*)(wsf + OFF_FRAC/4 + 4*atom);
    const float* kt = wsf + OFF_KTAB/4;
    const float* SrW = wsf + OFF_SRW/4;
    const float* SiW = wsf + OFF_SIW/4;
    float acc = 0.f;
    int k0 = kc*128;
    for (int j=0;j<128;j++) {
        int k = k0 + j;
        float4 g = *(const float4*)(kt + 4*k);
        float u = g.x*f.x + g.y*f.y + g.z*f.z;
        float s,c; sc_frac(u, s, c);
        acc = fmaf(c, SrW[k], fmaf(s, SiW[k], acc));
    }
    wsf[OFF_BPART/4 + kc*NM + m] = acc;
}

// -------- B = -field; init CG residuals r1=B, r2=1 --------
__global__ void k_bfinal(float* __restrict__ wsf) {
    int m = blockIdx.x*256 + threadIdx.x;
    float s = 0.f;
    for (int kc=0;kc<62;kc++) s += wsf[OFF_BPART/4 + kc*NM + m];
    float B = -s;
    wsf[OFF_B/4 + m] = B;
    float* vec = wsf + OFF_VEC/4;
    vec[4096 + m] = B;    // r1
    vec[6144 + m] = 1.f;  // r2
}

// -------- A build: triangular 64x64 tiles, K-split x4 (blockIdx.y), atomicAdd --------
__launch_bounds__(256)
__global__ void k_abuild(float* __restrict__ wsf) {
    __shared__ float cwi[32][64], swi[32][64], cjs[32][64], sjs[32][64];
    __shared__ float4 fi[64], fj[64];
    int tid = threadIdx.x;
    int bid = blockIdx.x;
    int kq  = blockIdx.y;
    int bi = (int)((sqrtf(8.f*bid + 1.f) - 1.f)*0.5f);
    while ((bi+1)*(bi+2)/2 <= bid) bi++;
    while (bi*(bi+1)/2 > bid) bi--;
    int bj = bid - bi*(bi+1)/2;

    const int* mlist = (const int*)wsf + OFF_MLIST/4;
    const float* frac = wsf + OFF_FRAC/4;
    const float* ktab = wsf + OFF_KTAB/4;

    if (tid < 64)        fi[tid]     = *(const float4*)(frac + 4*mlist[bi*64 + tid]);
    else if (tid < 128)  fj[tid-64]  = *(const float4*)(frac + 4*mlist[bj*64 + (tid-64)]);
    __syncthreads();

    int col = tid & 63;
    int kkb = tid >> 6;       // 0..3
    float4 fir = fi[col];
    float4 fjr = fj[col];
    int ty = tid >> 4, tx = tid & 15;
    int ty4 = ty*4, tx4 = tx*4;
    float acc[4][4] = {};

    for (int k0=kq*KQ; k0<(kq+1)*KQ; k0+=32) {
        #pragma unroll
        for (int it=0; it<8; it++) {
            int kk = kkb + it*4;
            float4 kt = *(const float4*)(ktab + 4*(k0+kk));
            float u = kt.x*fir.x + kt.y*fir.y + kt.z*fir.z;
            float s,c; sc_frac(u, s, c);
            cwi[kk][col] = kt.w*c; swi[kk][col] = kt.w*s;
            u = kt.x*fjr.x + kt.y*fjr.y + kt.z*fjr.z;
            sc_frac(u, s, c);
            cjs[kk][col] = c; sjs[kk][col] = s;
        }
        __syncthreads();
        #pragma unroll 4
        for (int kk=0; kk<32; kk++) {
            float4 ac  = *(const float4*)&cwi[kk][ty4];
            float4 as2 = *(const float4*)&swi[kk][ty4];
            float4 bc  = *(const float4*)&cjs[kk][tx4];
            float4 bs  = *(const float4*)&sjs[kk][tx4];
            float aC[4] = {ac.x, ac.y, ac.z, ac.w};
            float aS[4] = {as2.x, as2.y, as2.z, as2.w};
            float bC[4] = {bc.x, bc.y, bc.z, bc.w};
            float bS[4] = {bs.x, bs.y, bs.z, bs.w};
            #pragma unroll
            for (int a=0;a<4;a++)
                #pragma unroll
                for (int b=0;b<4;b++)
                    acc[a][b] = fmaf(aC[a], bC[b], fmaf(aS[a], bS[b], acc[a][b]));
        }
        __syncthreads();
    }

    float* A = wsf + OFF_A/4;
    int gi0 = bi*64 + ty4, gj0 = bj*64 + tx4;
    if (bi == bj) {
        #pragma unroll
        for (int a=0;a<4;a++)
            #pragma unroll
            for (int b=0;b<4;b++)
                atomicAdd(&A[(size_t)(gi0+a)*NM + gj0+b], acc[a][b]);
    } else {
        #pragma unroll
        for (int a=0;a<4;a++)
            #pragma unroll
            for (int b=0;b<4;b++) {
                float v = acc[a][b];
                atomicAdd(&A[(size_t)(gi0+a)*NM + gj0+b], v);
                atomicAdd(&A[(size_t)(gj0+b)*NM + gi0+a], v);
            }
    }
}

// -------- persistent CG: 1 flag-barrier/iter, w-row exchange only --------
// 256 blocks x 256 threads. Block owns rows [bid*8, bid*8+8) for the matvec
// (32 lanes/row). Thread owns float4 chunks {4t..4t+3, 1024+4t..1024+4t+3}
// of the full vectors (conflict-free LDS, coalesced 8B gathers).
// Full r (LDS) and s (regs) replicated bit-identically in every block.
__launch_bounds__(256, 1)
__global__ void k_cg(float* __restrict__ wsf) {
    const float* A = wsf + OFF_A/4;
    float* vec = wsf + OFF_VEC/4;
    float* x1g = vec;              float* x2g = vec + 2048;
    const float* r1g = vec + 4096; const float* r2g = vec + 6144;
    int* flags = (int*)wsf + OFF_FLAGS/4;
    float* wbuf = wsf + OFF_WBUF/4;      // [parity][rhs][NM]

    __shared__ float r1s[NM], r2s[NM];
    __shared__ float red[16];            // 4 waves x {g1,d1,g2,d2}

    int tid = threadIdx.x, bid = blockIdx.x;
    int rl = tid >> 5, lane = tid & 31;
    int row = bid*8 + rl;
    const float* Arow = A + (size_t)row*NM;
    int ca = 4*tid;            // own chunk A: elements ca..ca+3
    int cb = 1024 + 4*tid;     // own chunk B

    for (int i=tid; i<NM/4; i+=256) {
        ((float4*)r1s)[i] = ((const float4*)r1g)[i];
        ((float4*)r2s)[i] = ((const float4*)r2g)[i];
    }
    __syncthreads();

    float s1a[4]={0,0,0,0}, s1b[4]={0,0,0,0};
    float s2a[4]={0,0,0,0}, s2b[4]={0,0,0,0};
    float p1r=0.f, p2r=0.f, x1r=0.f, x2r=0.f;    // own-row p/x (tid<8 only)
    float gp1=1.f, ap1=1.f, gp2=1.f, ap2=1.f;

    for (int iter=0; iter<NIT; ++iter) {
        // ---- w_own = A_own x r (2 RHS), 32 lanes per row ----
        float acc1=0.f, acc2=0.f;
        #pragma unroll 8
        for (int c=lane*4; c<NM; c+=128) {
            float4 a  = *(const float4*)(Arow + c);
            float4 u1 = *(const float4*)(r1s + c);
            float4 u2 = *(const float4*)(r2s + c);
            acc1 += a.x*u1.x + a.y*u1.y + a.z*u1.z + a.w*u1.w;
            acc2 += a.x*u2.x + a.y*u2.y + a.z*u2.z + a.w*u2.w;
        }
        #pragma unroll
        for (int off=1; off<32; off<<=1) {
            acc1 += __shfl_xor(acc1, off);
            acc2 += __shfl_xor(acc2, off);
        }
        float* wb = wbuf + (iter&1)*4096;
        if (lane == 0) {
            __hip_atomic_store(wb + row,        acc1, __ATOMIC_RELAXED, __HIP_MEMORY_SCOPE_AGENT);
            __hip_atomic_store(wb + 2048 + row, acc2, __ATOMIC_RELAXED, __HIP_MEMORY_SCOPE_AGENT);
        }
        __syncthreads();   // drains w stores (vmcnt) before flag release
        // ---- flag barrier: release own flag, wave0 packed-polls 256 flags ----
        if (tid == 0)
            __hip_atomic_store(&flags[bid], iter+1, __ATOMIC_RELEASE, __HIP_MEMORY_SCOPE_AGENT);
        if (tid < 64) {
            unsigned long long* f8 = (unsigned long long*)flags;
            for (;;) {
                unsigned long long v0 = __hip_atomic_load(&f8[2*tid],   __ATOMIC_RELAXED, __HIP_MEMORY_SCOPE_AGENT);
                unsigned long long v1 = __hip_atomic_load(&f8[2*tid+1], __ATOMIC_RELAXED, __HIP_MEMORY_SCOPE_AGENT);
                int t = iter+1;
                int ok = ((int)(v0 & 0xffffffffu) >= t) & ((int)(v0>>32) >= t)
                       & ((int)(v1 & 0xffffffffu) >= t) & ((int)(v1>>32) >= t);
                if (__all(ok)) break;
                __builtin_amdgcn_s_sleep(1);
            }
        }
        __syncthreads();
        // ---- gather own w chunks: coalesced 8B device-coherent loads ----
        float2 w1a0 = ld_f2_agent(wb + ca),        w1a1 = ld_f2_agent(wb + ca + 2);
        float2 w1b0 = ld_f2_agent(wb + cb),        w1b1 = ld_f2_agent(wb + cb + 2);
        float2 w2a0 = ld_f2_agent(wb + 2048 + ca), w2a1 = ld_f2_agent(wb + 2048 + ca + 2);
        float2 w2b0 = ld_f2_agent(wb + 2048 + cb), w2b1 = ld_f2_agent(wb + 2048 + cb + 2);
        float w1[8] = {w1a0.x,w1a0.y,w1a1.x,w1a1.y, w1b0.x,w1b0.y,w1b1.x,w1b1.y};
        float w2[8] = {w2a0.x,w2a0.y,w2a1.x,w2a1.y, w2b0.x,w2b0.y,w2b1.x,w2b1.y};
        // ---- own r chunks (clean b128 LDS reads) ----
        float4 r1a = *(const float4*)(r1s + ca), r1b = *(const float4*)(r1s + cb);
        float4 r2a = *(const float4*)(r2s + ca), r2b = *(const float4*)(r2s + cb);
        float r1[8] = {r1a.x,r1a.y,r1a.z,r1a.w, r1b.x,r1b.y,r1b.z,r1b.w};
        float r2[8] = {r2a.x,r2a.y,r2a.z,r2a.w, r2b.x,r2b.y,r2b.z,r2b.w};
        // ---- dots gamma=(r,r), delta=(r,w), deterministic reduce ----
        float g1=0.f,d1=0.f,g2=0.f,d2=0.f;
        #pragma unroll
        for (int j=0;j<8;j++) {
            g1 = fmaf(r1[j],r1[j],g1); d1 = fmaf(r1[j],w1[j],d1);
            g2 = fmaf(r2[j],r2[j],g2); d2 = fmaf(r2[j],w2[j],d2);
        }
        #pragma unroll
        for (int off=1; off<64; off<<=1) {
            g1 += __shfl_xor(g1,off); d1 += __shfl_xor(d1,off);
            g2 += __shfl_xor(g2,off); d2 += __shfl_xor(d2,off);
        }
        if ((tid&63)==0) { int w=tid>>6; red[w*4+0]=g1; red[w*4+1]=d1; red[w*4+2]=g2; red[w*4+3]=d2; }
        __syncthreads();
        g1 = red[0]+red[4]+red[8]+red[12];
        d1 = red[1]+red[5]+red[9]+red[13];
        g2 = red[2]+red[6]+red[10]+red[14];
        d2 = red[3]+red[7]+red[11]+red[15];
        // ---- identical scalar recurrences in every thread/block ----
        float b1,a1,b2,a2;
        if (iter == 0) { b1=0.f; a1=g1/d1; b2=0.f; a2=g2/d2; }
        else {
            b1 = g1/gp1; a1 = g1/(d1 - b1*g1/ap1);
            b2 = g2/gp2; a2 = g2/(d2 - b2*g2/ap2);
        }
        gp1=g1; ap1=a1; gp2=g2; ap2=a2;
        // ---- p/x for own rows (reads OLD r cross-thread; before r writes) ----
        if (tid < 8) {
            float rv1 = r1s[bid*8+tid], rv2 = r2s[bid*8+tid];
            p1r = (iter==0) ? rv1 : fmaf(b1, p1r, rv1);
            p2r = (iter==0) ? rv2 : fmaf(b2, p2r, rv2);
            x1r = (iter==0) ? a1*p1r : fmaf(a1, p1r, x1r);
            x2r = (iter==0) ? a2*p2r : fmaf(a2, p2r, x2r);
        }
        __syncthreads();
        // ---- s (regs) and r (LDS, float4 chunk writes) updates ----
        float nr1[8], nr2[8];
        #pragma unroll
        for (int j=0;j<4;j++) {
            float sv1 = (iter==0) ? w1[j] : fmaf(b1, s1a[j], w1[j]);
            float sv2 = (iter==0) ? w2[j] : fmaf(b2, s2a[j], w2[j]);
            s1a[j]=sv1; s2a[j]=sv2;
            nr1[j] = fmaf(-a1, sv1, r1[j]);
            nr2[j] = fmaf(-a2, sv2, r2[j]);
        }
        #pragma unroll
        for (int j=0;j<4;j++) {
            float sv1 = (iter==0) ? w1[4+j] : fmaf(b1, s1b[j], w1[4+j]);
            float sv2 = (iter==0) ? w2[4+j] : fmaf(b2, s2b[j], w2[4+j]);
            s1b[j]=sv1; s2b[j]=sv2;
            nr1[4+j] = fmaf(-a1, sv1, r1[4+j]);
            nr2[4+j] = fmaf(-a2, sv2, r2[4+j]);
        }
        *(float4*)(r1s + ca) = make_float4(nr1[0],nr1[1],nr1[2],nr1[3]);
        *(float4*)(r1s + cb) = make_float4(nr1[4],nr1[5],nr1[6],nr1[7]);
        *(float4*)(r2s + ca) = make_float4(nr2[0],nr2[1],nr2[2],nr2[3]);
        *(float4*)(r2s + cb) = make_float4(nr2[4],nr2[5],nr2[6],nr2[7]);
        __syncthreads();
    }
    if (tid < 8) { x1g[bid*8+tid] = x1r; x2g[bid*8+tid] = x2r; }
}

// -------- lambda = sum(x1)/sum(x2) --------
__global__ void k_sum(float* __restrict__ wsf) {
    int tid = threadIdx.x;
    float* vec = wsf + OFF_VEC/4;
    float s1=0.f, s2=0.f;
    for (int i=tid; i<NM; i+=256) { s1 += vec[i]; s2 += vec[2048+i]; }
    __shared__ float a[256], b[256];
    a[tid]=s1; b[tid]=s2; __syncthreads();
    for (int off=128; off>0; off>>=1) {
        if (tid<off) { a[tid]+=a[tid+off]; b[tid]+=b[tid+off]; }
        __syncthreads();
    }
    if (tid==0) wsf[OFF_SUMS/4 + 2] = a[0]/b[0];
}

// -------- assemble output --------
__global__ void k_out(const float* __restrict__ q, const int* __restrict__ an,
                      const float* __restrict__ wsf, float* __restrict__ out) {
    int i = blockIdx.x*256 + threadIdx.x;
    if (i >= NA) return;
    if (an[i]==METAL_Z) {
        int p = ((const int*)wsf)[OFF_POSOF/4 + i];
        float lam = wsf[OFF_SUMS/4 + 2];
        const float* vec = wsf + OFF_VEC/4;
        out[i] = vec[p] - lam*vec[2048 + p];
    } else {
        out[i] = q[i];
    }
}

extern "C" void kernel_launch(void* const* d_in, const int* in_sizes, int n_in,
                              void* d_out, int out_size, void* d_ws, size_t ws_size,
                              hipStream_t stream) {
    (void)in_sizes; (void)n_in; (void)out_size; (void)ws_size;
    const float* pos  = (const float*)d_in[0];
    const float* cell = (const float*)d_in[1];
    const float* q    = (const float*)d_in[2];
    const float* Jraw = (const float*)d_in[3];
    const int*   an   = (const int*)d_in[4];
    float* wsf = (float*)d_ws;
    float* out = (float*)d_out;

    k_setup<<<1, 256, 0, stream>>>(pos, cell, Jraw, an, wsf);
    k_azero<<<1024, 256, 0, stream>>>(wsf);
    k_ktab<<<KHP/256, 256, 0, stream>>>(wsf);
    k_srsi<<<KHP, 256, 0, stream>>>(q, an, wsf);
    k_field<<<dim3(62, 8), 256, 0, stream>>>(wsf);
    k_bfinal<<<NM/256, 256, 0, stream>>>(wsf);
    k_abuild<<<dim3(528, 4), 256, 0, stream>>>(wsf);
    k_cg<<<NBLK_CG, 256, 0, stream>>>(wsf);
    k_sum<<<1, 256, 0, stream>>>(wsf);
    k_out<<<NA/256, 256, 0, stream>>>(q, an, wsf, out);
}